// Round 6
// baseline (658.503 us; speedup 1.0000x reference)
//
#include <hip/hip_runtime.h>
#include <math.h>

#define NB 32768
#define EPS_REC 1e-4f

// Inter-stage staging (static device globals: graph-capture safe).
__device__ float g_x2[NB * 256];  // stage-1 output: B x 16 x 16
__device__ float g_x3[NB * 16];   // stage-2 output: B x 4 x 4

// HISTORY (do not regress):
//  R5: dual-chain ILP -> occupancy halved, +22% time.
//  R6: __launch_bounds__(128,6) -> 85-reg cap -> spills (FETCH 407MB), +60%.
//  R8: 3 sweeps -> absmax 1.375 FAIL. 4 sweeps minimum (plateau 0.25).
//  R9/R10: two-sided, U in regs: 641us. VALU busy-time ~405us.
//  R11: U in LDS: VALU busy UNCHANGED, +10% (b128 LDS ops). Mixed bound.
//  R12: ONE-SIDED Jacobi (col in regs, DPP partner, bpermute tournament):
//       PASSED but FETCH 492/WRITE 961MB scratch, 894us.
//  R13: swp[] deleted: FETCH 441/WRITE 868. VGPR=64.
//  R14: hot state as named float4 SSA: FETCH/WRITE byte-identical to R13.
//  R15: amdgpu_waves_per_eu(4,4): INERT (VGPR 64, scratch unchanged).
//       Unified diagnosis: backend targets 8 waves/EU -> 64-VGPR cap;
//       scheduler batches 20 bperm+fmaf temps to hide LDS-crossbar latency
//       -> ~60-reg hot live set -> a few per-round spills x 76 rounds x
//       699k threads = the ~1.3GB. Measured occupancy is only ~40%
//       (1-wave-WG dispatch-limited) so the 64-cap buys NOTHING at runtime.
//  R16 (this): force budget via the LDS occupancy constraint (compile-time
//       visible, can't be ignored): pad static LDS to 12.2KB/WG -> 13
//       WGs/CU -> ~3 waves/EU target -> VGPR budget ~168 -> no spill.
//       Runtime occupancy unchanged (13 waves/CU = the measured 40%).
__device__ __forceinline__ void wsync() {
  asm volatile("" ::: "memory");
  __builtin_amdgcn_wave_barrier();
  asm volatile("" ::: "memory");
}

// Swap values between adjacent lanes (lane ^ 1) via DPP quad_perm [1,0,3,2].
// Pairs (2k,2k+1) are even-aligned so they never cross a quad. VALU-pipe op.
__device__ __forceinline__ float dpp_swap1(float x) {
  int xi = __builtin_bit_cast(int, x);
  int yi = __builtin_amdgcn_update_dpp(xi, xi, 0xB1, 0xF, 0xF, true);
  return __builtin_bit_cast(float, yi);
}

// Lane-pull via LDS crossbar (conflict-free permutation). addr = 4*srcLane.
__device__ __forceinline__ float bperm(int addr, float v) {
  int r = __builtin_amdgcn_ds_bpermute(addr, __builtin_bit_cast(int, v));
  return __builtin_bit_cast(float, r);
}

// Tournament (circle-method): content of slot s moves to permf(s); with fixed
// pairing (2k,2k+1), every pair meets exactly once per N-1 rounds.
// srcslot = permf^{-1}: the slot whose content lands in slot `sub`.
__device__ __forceinline__ int srcslot(int sub, int n) {
  return sub == 0 ? 0
       : sub == 1 ? 2
       : sub == n - 2 ? n - 1
       : (sub & 1) ? sub - 2 : sub + 2;
}

// Jacobi rotation (c,s) zeroing the (p,q) off-diagonal of the 2x2 Gram
// [[app,apq],[apq,aqq]]; G = [[c,s],[-s,c]].
__device__ __forceinline__ void rot_cs(float app, float aqq, float apq,
                                       float& c, float& s) {
  float dd = 0.5f * (app - aqq);
  float q2 = apq * apq;
  float hh = dd * dd + q2 + 1e-30f;
  float h = sqrtf(hh);
  float u = fabsf(dd) + h;
  float gi = rsqrtf(u * u + q2);
  c = u * gi;
  float smag = apq * gi;
  s = (dd >= 0.f) ? -smag : smag;
}

// Gram partial: d += <own, partner>, n += <own, own> for 4 components.
__device__ __forceinline__ void gram4(float4 a, float& d0, float& d1,
                                      float& d2, float& d3, float& n0,
                                      float& n1, float& n2, float& n3) {
  float s0 = dpp_swap1(a.x);
  d0 += a.x * s0;
  n0 += a.x * a.x;
  float s1 = dpp_swap1(a.y);
  d1 += a.y * s1;
  n1 += a.y * a.y;
  float s2 = dpp_swap1(a.z);
  d2 += a.z * s2;
  n2 += a.z * a.z;
  float s3 = dpp_swap1(a.w);
  d3 += a.w * s3;
  n3 += a.w * a.w;
}

// Apply rotation + tournament move for 4 components. DPP reads pre-update
// partner values (both pair lanes are at the same program point, and the
// result goes to a fresh value, not back into a before all reads complete).
__device__ __forceinline__ float4 appmv4(float4 a, float c, float beta,
                                         int bpAddr) {
  float4 r;
  r.x = bperm(bpAddr, fmaf(beta, dpp_swap1(a.x), c * a.x));
  r.y = bperm(bpAddr, fmaf(beta, dpp_swap1(a.y), c * a.y));
  r.z = bperm(bpAddr, fmaf(beta, dpp_swap1(a.z), c * a.z));
  r.w = bperm(bpAddr, fmaf(beta, dpp_swap1(a.w), c * a.w));
  return r;
}

// One one-sided Jacobi round on a 20-row column held in a0..a4.
__device__ __forceinline__ void round20(float4& a0, float4& a1, float4& a2,
                                        float4& a3, float4& a4, int bpAddr,
                                        bool isP) {
  float d0 = 0.f, d1 = 0.f, d2 = 0.f, d3 = 0.f;
  float n0 = 0.f, n1 = 0.f, n2 = 0.f, n3 = 0.f;
  gram4(a0, d0, d1, d2, d3, n0, n1, n2, n3);
  gram4(a1, d0, d1, d2, d3, n0, n1, n2, n3);
  gram4(a2, d0, d1, d2, d3, n0, n1, n2, n3);
  gram4(a3, d0, d1, d2, d3, n0, n1, n2, n3);
  gram4(a4, d0, d1, d2, d3, n0, n1, n2, n3);
  float d = (d0 + d1) + (d2 + d3);
  float nOwn = (n0 + n1) + (n2 + n3);
  float nPrt = dpp_swap1(nOwn);
  float ne = isP ? nOwn : nPrt;  // canonical order: both pair lanes identical
  float no = isP ? nPrt : nOwn;
  float c, s;
  rot_cs(ne, no, d, c, s);
  float beta = isP ? -s : s;
  a0 = appmv4(a0, c, beta, bpAddr);
  a1 = appmv4(a1, c, beta, bpAddr);
  a2 = appmv4(a2, c, beta, bpAddr);
  a3 = appmv4(a3, c, beta, bpAddr);
  a4 = appmv4(a4, c, beta, bpAddr);
}

// One one-sided Jacobi round on a 16-row column held in b0..b3.
__device__ __forceinline__ void round16(float4& b0, float4& b1, float4& b2,
                                        float4& b3, int bpAddr, bool isP) {
  float d0 = 0.f, d1 = 0.f, d2 = 0.f, d3 = 0.f;
  float n0 = 0.f, n1 = 0.f, n2 = 0.f, n3 = 0.f;
  gram4(b0, d0, d1, d2, d3, n0, n1, n2, n3);
  gram4(b1, d0, d1, d2, d3, n0, n1, n2, n3);
  gram4(b2, d0, d1, d2, d3, n0, n1, n2, n3);
  gram4(b3, d0, d1, d2, d3, n0, n1, n2, n3);
  float d = (d0 + d1) + (d2 + d3);
  float nOwn = (n0 + n1) + (n2 + n3);
  float nPrt = dpp_swap1(nOwn);
  float ne = isP ? nOwn : nPrt;
  float no = isP ? nPrt : nOwn;
  float c, s;
  rot_cs(ne, no, d, c, s);
  float beta = isP ? -s : s;
  b0 = appmv4(b0, c, beta, bpAddr);
  b1 = appmv4(b1, c, beta, bpAddr);
  b2 = appmv4(b2, c, beta, bpAddr);
  b3 = appmv4(b3, c, beta, bpAddr);
}

__device__ __forceinline__ float sq4(float4 a) {
  return (a.x * a.x + a.y * a.y) + (a.z * a.z + a.w * a.w);
}

// LDS pad: groups use ZB[0..300); [300..748) is an occupancy governor.
// Static LDS 12.2KB/WG -> 13 WGs/CU -> backend VGPR budget ~168 (see R16).
#define ZB_PAD 448
#define Y3_PAD 688

// Stage 1: X1 = w1^T X w1 (19 padded to 20), one-sided Jacobi, then
// X2 = Y^T Lamc Y with Y[j] = w2^T u_j. 3 matrices per wave (lanes 60..63
// masked by early return), 64-thread blocks = 1 wave = 3 matrices.
__global__ __launch_bounds__(64)
__attribute__((amdgpu_waves_per_eu(4, 4))) void spd_stage1(
    const float* __restrict__ x, const float* __restrict__ w1,
    const float* __restrict__ w2) {
  __shared__ float4 ZB[3 * 100 + ZB_PAD];  // Z staging + occupancy pad
  __shared__ float SL[3 * 20];
  int lane = threadIdx.x;
  int gl = lane / 20;  // 0..3 (3 = idle lanes 60..63)
  int sub = lane - gl * 20;
  int b = blockIdx.x * 3 + gl;
  if (gl >= 3 || b >= NB) return;  // no __syncthreads anywhere: safe
  float4* ZB4 = ZB + gl * 100;
  float* ZBf = (float*)ZB4;
  float* SLg = SL + gl * 20;

  // ---- bilinear: Z = w1^T X (col sub), then X1 col sub = (Z w1) col ----
  const float* xb = x + b * 361;
  float cx[19];
#pragma unroll
  for (int i = 0; i < 19; ++i) cx[i] = (sub < 19) ? xb[i * 19 + sub] : 0.f;
  float z[20];
  z[19] = 0.f;
#pragma unroll
  for (int i = 0; i < 19; ++i) {
    float acc = 0.f;
#pragma unroll
    for (int r = 0; r < 19; ++r) acc += w1[r * 19 + i] * cx[r];
    z[i] = acc;
  }
#pragma unroll
  for (int t = 0; t < 5; ++t)
    ZB4[t * 20 + sub] =
        make_float4(z[4 * t], z[4 * t + 1], z[4 * t + 2], z[4 * t + 3]);
  wsync();
  float wj[19];
#pragma unroll
  for (int r = 0; r < 19; ++r) wj[r] = (sub < 19) ? w1[r * 19 + sub] : 0.f;
  float4 a0 = make_float4(0.f, 0.f, 0.f, 0.f);
  float4 a1 = a0, a2 = a0, a3 = a0, a4 = a0;
#pragma unroll
  for (int r = 0; r < 19; ++r) {
    float wr = wj[r];
    float4 zc;
    zc = ZB4[0 * 20 + r];
    a0.x += zc.x * wr; a0.y += zc.y * wr; a0.z += zc.z * wr; a0.w += zc.w * wr;
    zc = ZB4[1 * 20 + r];
    a1.x += zc.x * wr; a1.y += zc.y * wr; a1.z += zc.z * wr; a1.w += zc.w * wr;
    zc = ZB4[2 * 20 + r];
    a2.x += zc.x * wr; a2.y += zc.y * wr; a2.z += zc.z * wr; a2.w += zc.w * wr;
    zc = ZB4[3 * 20 + r];
    a3.x += zc.x * wr; a3.y += zc.y * wr; a3.z += zc.z * wr; a3.w += zc.w * wr;
    zc = ZB4[4 * 20 + r];
    a4.x += zc.x * wr; a4.y += zc.y * wr; a4.z += zc.z * wr; a4.w += zc.w * wr;
  }
  // a0..a4 = X1 column sub; pad column 19 is exactly 0 (stays 0: d=0 => s=0).

  const int bpAddr = (gl * 20 + srcslot(sub, 20)) * 4;
  const bool isP = !(sub & 1);
#pragma unroll 1
  for (int it = 0; it < 76; ++it)  // 4 sweeps (validated minimum)
    round20(a0, a1, a2, a3, a4, bpAddr, isP);

  // lambda_j = ||col||, u_j = col/||col|| (guarded for the zero pad column)
  float nOwn = ((sq4(a0) + sq4(a1)) + (sq4(a2) + sq4(a3))) + sq4(a4);
  float lamc = fmaxf(sqrtf(nOwn), EPS_REC);
  float nrm = nOwn + 1e-30f;
  float inv = rsqrtf(nrm);
  inv = inv * (1.5f - 0.5f * nrm * inv * inv);  // 1 NR step
  // Unpack to a short-lived static array for the tail.
  float cv[20];
  cv[0] = a0.x; cv[1] = a0.y; cv[2] = a0.z; cv[3] = a0.w;
  cv[4] = a1.x; cv[5] = a1.y; cv[6] = a1.z; cv[7] = a1.w;
  cv[8] = a2.x; cv[9] = a2.y; cv[10] = a2.z; cv[11] = a2.w;
  cv[12] = a3.x; cv[13] = a3.y; cv[14] = a3.z; cv[15] = a3.w;
  cv[16] = a4.x; cv[17] = a4.y; cv[18] = a4.z; cv[19] = a4.w;
  // y[k] = sum_{i<19} w2[i][k] * u_j[i]   (in-lane; w2 uniform -> scalar lds)
  float y[16];
#pragma unroll
  for (int k = 0; k < 16; ++k) y[k] = 0.f;
#pragma unroll
  for (int i = 0; i < 19; ++i) {
    float ui = cv[i];
#pragma unroll
    for (int k = 0; k < 16; ++k) y[k] += w2[i * 16 + k] * ui;
  }
#pragma unroll
  for (int k = 0; k < 16; ++k) y[k] *= inv;
  wsync();  // Z staging dead; reuse ZB for Y rows
  SLg[sub] = lamc;
#pragma unroll
  for (int t = 0; t < 4; ++t)
    ZB4[sub * 4 + t] =
        make_float4(y[4 * t], y[4 * t + 1], y[4 * t + 2], y[4 * t + 3]);
  wsync();
  // X2[i][sub] = sum_j lamc_j Y[j][i] Y[j][sub]
  if (sub < 16) {
    float acc[16];
#pragma unroll
    for (int i = 0; i < 16; ++i) acc[i] = 0.f;
#pragma unroll
    for (int r = 0; r < 20; ++r) {
      float pr = SLg[r] * ZBf[r * 16 + sub];
#pragma unroll
      for (int t = 0; t < 4; ++t) {
        float4 yr = ZB4[r * 4 + t];  // Y row r, cols 4t..4t+3 (broadcast)
        acc[4 * t + 0] += pr * yr.x;
        acc[4 * t + 1] += pr * yr.y;
        acc[4 * t + 2] += pr * yr.z;
        acc[4 * t + 3] += pr * yr.w;
      }
    }
    float* outb = g_x2 + b * 256;
#pragma unroll
    for (int i = 0; i < 16; ++i) outb[i * 16 + sub] = acc[i];
  }
}

// Stage 2: one-sided Jacobi on 16x16, X3 = Y3^T Lamc Y3 with Y3[j]=w3^T u_j.
// 4 matrices per wave, 64-thread blocks, all lanes active.
__global__ __launch_bounds__(64)
__attribute__((amdgpu_waves_per_eu(4, 4))) void spd_stage2(
    const float* __restrict__ w3) {
  __shared__ float4 Y3L[4 * 16 + Y3_PAD];  // Y3 + occupancy pad
  __shared__ float SL2[4 * 16];
  int lane = threadIdx.x;
  int gl = lane >> 4;
  int sub = lane & 15;
  int b = blockIdx.x * 4 + gl;
  float* Y3f = (float*)(Y3L + gl * 16);
  float* SLg = SL2 + gl * 16;

  const float* xb = g_x2 + b * 256;
  float4 b0 = make_float4(xb[0 * 16 + sub], xb[1 * 16 + sub], xb[2 * 16 + sub],
                          xb[3 * 16 + sub]);
  float4 b1 = make_float4(xb[4 * 16 + sub], xb[5 * 16 + sub], xb[6 * 16 + sub],
                          xb[7 * 16 + sub]);
  float4 b2 = make_float4(xb[8 * 16 + sub], xb[9 * 16 + sub],
                          xb[10 * 16 + sub], xb[11 * 16 + sub]);
  float4 b3 = make_float4(xb[12 * 16 + sub], xb[13 * 16 + sub],
                          xb[14 * 16 + sub], xb[15 * 16 + sub]);

  const int bpAddr = (gl * 16 + srcslot(sub, 16)) * 4;
  const bool isP = !(sub & 1);
#pragma unroll 1
  for (int it = 0; it < 60; ++it)  // 4 sweeps
    round16(b0, b1, b2, b3, bpAddr, isP);

  float nOwn = (sq4(b0) + sq4(b1)) + (sq4(b2) + sq4(b3));
  float lamc = fmaxf(sqrtf(nOwn), EPS_REC);
  float nrm = nOwn + 1e-30f;
  float inv = rsqrtf(nrm);
  inv = inv * (1.5f - 0.5f * nrm * inv * inv);
  float cv[16];
  cv[0] = b0.x; cv[1] = b0.y; cv[2] = b0.z; cv[3] = b0.w;
  cv[4] = b1.x; cv[5] = b1.y; cv[6] = b1.z; cv[7] = b1.w;
  cv[8] = b2.x; cv[9] = b2.y; cv[10] = b2.z; cv[11] = b2.w;
  cv[12] = b3.x; cv[13] = b3.y; cv[14] = b3.z; cv[15] = b3.w;
  float y3[4] = {0.f, 0.f, 0.f, 0.f};
#pragma unroll
  for (int i = 0; i < 16; ++i) {
    float ui = cv[i];
#pragma unroll
    for (int j = 0; j < 4; ++j) y3[j] += w3[i * 4 + j] * ui;
  }
#pragma unroll
  for (int j = 0; j < 4; ++j) y3[j] *= inv;
  SLg[sub] = lamc;
  ((float4*)Y3f)[sub] = make_float4(y3[0], y3[1], y3[2], y3[3]);
  wsync();
  int ii = sub >> 2, jj = sub & 3;
  float acc = 0.f;
#pragma unroll
  for (int r = 0; r < 16; ++r)
    acc += SLg[r] * Y3f[r * 4 + ii] * Y3f[r * 4 + jj];
  g_x3[b * 16 + sub] = acc;
}

// Stage 3: per-thread 4x4 LogEig in registers, FC(16->2), log_softmax.
__global__ __launch_bounds__(256) void spd_stage3(const float* __restrict__ fcw,
                                                  float* __restrict__ out) {
  int b = blockIdx.x * 256 + threadIdx.x;
  const float* xb = g_x3 + b * 16;
  float a[4][4];
#pragma unroll
  for (int i = 0; i < 4; ++i)
#pragma unroll
    for (int j = 0; j < 4; ++j) a[i][j] = xb[i * 4 + j];
  float vv[4][4];
#pragma unroll
  for (int i = 0; i < 4; ++i)
#pragma unroll
    for (int j = 0; j < 4; ++j) vv[i][j] = (i == j) ? 1.f : 0.f;

  constexpr int P4[6] = {0, 0, 0, 1, 1, 2};
  constexpr int Q4[6] = {1, 2, 3, 2, 3, 3};
  for (int sw = 0; sw < 6; ++sw) {
#pragma unroll
    for (int e = 0; e < 6; ++e) {
      const int p = P4[e], q = Q4[e];
      float c, s;
      rot_cs(a[p][p], a[q][q], a[p][q], c, s);
#pragma unroll
      for (int j = 0; j < 4; ++j) {
        float xx = a[p][j], yy = a[q][j];
        a[p][j] = c * xx - s * yy;
        a[q][j] = s * xx + c * yy;
      }
#pragma unroll
      for (int i = 0; i < 4; ++i) {
        float xx = a[i][p], yy = a[i][q];
        a[i][p] = c * xx - s * yy;
        a[i][q] = s * xx + c * yy;
      }
#pragma unroll
      for (int i = 0; i < 4; ++i) {
        float xx = vv[i][p], yy = vv[i][q];
        vv[i][p] = c * xx - s * yy;
        vv[i][q] = s * xx + c * yy;
      }
    }
  }
  float ll[4];
#pragma unroll
  for (int r = 0; r < 4; ++r) ll[r] = logf(fmaxf(a[r][r], 1e-12f));
  float feat[16];
#pragma unroll
  for (int i = 0; i < 4; ++i)
#pragma unroll
    for (int j = 0; j < 4; ++j) {
      float acc = 0.f;
#pragma unroll
      for (int r = 0; r < 4; ++r) acc += ll[r] * vv[i][r] * vv[j][r];
      feat[i * 4 + j] = acc;
    }
  float z0 = 0.f, z1 = 0.f;
#pragma unroll
  for (int k = 0; k < 16; ++k) {
    z0 += feat[k] * fcw[2 * k + 0];
    z1 += feat[k] * fcw[2 * k + 1];
  }
  float m = fmaxf(z0, z1);
  float lse = logf(expf(z0 - m) + expf(z1 - m));
  out[b * 2 + 0] = z0 - m - lse;
  out[b * 2 + 1] = z1 - m - lse;
#pragma unroll
  for (int k = 0; k < 16; ++k) out[2 * NB + b * 16 + k] = feat[k];
}

extern "C" void kernel_launch(void* const* d_in, const int* in_sizes, int n_in,
                              void* d_out, int out_size, void* d_ws,
                              size_t ws_size, hipStream_t stream) {
  (void)in_sizes;
  (void)n_in;
  (void)out_size;
  (void)d_ws;
  (void)ws_size;
  const float* x = (const float*)d_in[0];
  const float* w1 = (const float*)d_in[1];
  const float* w2 = (const float*)d_in[2];
  const float* w3 = (const float*)d_in[3];
  const float* fcw = (const float*)d_in[4];
  float* out = (float*)d_out;

  spd_stage1<<<(NB + 2) / 3, 64, 0, stream>>>(x, w1, w2);
  spd_stage2<<<NB / 4, 64, 0, stream>>>(w3);
  spd_stage3<<<NB / 256, 256, 0, stream>>>(fcw, out);
}

// Round 7
// 646.788 us; speedup vs baseline: 1.0181x; 1.0181x over previous
//
#include <hip/hip_runtime.h>
#include <math.h>

#define NB 32768
#define EPS_REC 1e-4f

// Inter-stage staging (static device globals: graph-capture safe).
__device__ float g_x2[NB * 256];  // stage-1 output: B x 16 x 16
__device__ float g_x3[NB * 16];   // stage-2 output: B x 4 x 4

// HISTORY (do not regress):
//  R5: dual-chain ILP -> occupancy halved, +22% time.
//  R6: __launch_bounds__(128,6) -> 85-reg cap -> spills (FETCH 407MB), +60%.
//  R8: 3 sweeps -> absmax 1.375 FAIL. 4 sweeps minimum (plateau 0.25).
//  R9/R10: two-sided, U in regs, 128-thr blocks: 641us, FETCH 23MB -- the
//       register-overflow path was AGPR shuttle (v_accvgpr), NOT scratch.
//  R11: U in LDS: VALU busy unchanged, +10% (b128 LDS ops). Mixed bound.
//       Shell = 128-thr blocks, valid-masking, (128,4): ZERO scratch.
//  R12: ONE-SIDED Jacobi + NEW SHELL (64-thr blocks, divergent early
//       return, bperm loop): algorithm PASSED (absmax 0.5) but scratch
//       appeared: FETCH 492/WRITE 961MB.
//  R13-R16: inside the new shell, ALL knobs inert on scratch+VGPR(=64):
//       swp[] removal (-144MB only), named-float4 SSA (byte-identical),
//       amdgpu_waves_per_eu(4,4) (inert), LDS pad to 12.2KB (occupancy
//       dropped 40->29.7 but VGPR/scratch unchanged). Conclusion: the
//       SHELL, not the hot-loop form or budget, triggers scratch (divergent
//       early-return CFG blocking SROA/AGPR-spill is the prime suspect).
//  R17 (this): one-sided algorithm transplanted into the PROVEN R11 shell:
//       128-thr blocks, 6 groups + shared dummy slot, bool-valid masking
//       (no early return), launch_bounds(128,4). Hot state stays named
//       float4 + bperm tournament. Dummy lanes run on zeros (c=1,s=0).
__device__ __forceinline__ void wsync() {
  asm volatile("" ::: "memory");
  __builtin_amdgcn_wave_barrier();
  asm volatile("" ::: "memory");
}

// Swap values between adjacent lanes (lane ^ 1) via DPP quad_perm [1,0,3,2].
// Pairs (2k,2k+1) are even-aligned so they never cross a quad. VALU-pipe op.
__device__ __forceinline__ float dpp_swap1(float x) {
  int xi = __builtin_bit_cast(int, x);
  int yi = __builtin_amdgcn_update_dpp(xi, xi, 0xB1, 0xF, 0xF, true);
  return __builtin_bit_cast(float, yi);
}

// Lane-pull via LDS crossbar (conflict-free permutation). addr = 4*srcLane
// (wave-relative lane index).
__device__ __forceinline__ float bperm(int addr, float v) {
  int r = __builtin_amdgcn_ds_bpermute(addr, __builtin_bit_cast(int, v));
  return __builtin_bit_cast(float, r);
}

// Tournament (circle-method): content of slot s moves to permf(s); with fixed
// pairing (2k,2k+1), every pair meets exactly once per N-1 rounds.
// srcslot = permf^{-1}: the slot whose content lands in slot `sub`.
__device__ __forceinline__ int srcslot(int sub, int n) {
  return sub == 0 ? 0
       : sub == 1 ? 2
       : sub == n - 2 ? n - 1
       : (sub & 1) ? sub - 2 : sub + 2;
}

// Jacobi rotation (c,s) zeroing the (p,q) off-diagonal of the 2x2 Gram
// [[app,apq],[apq,aqq]]; G = [[c,s],[-s,c]].
__device__ __forceinline__ void rot_cs(float app, float aqq, float apq,
                                       float& c, float& s) {
  float dd = 0.5f * (app - aqq);
  float q2 = apq * apq;
  float hh = dd * dd + q2 + 1e-30f;
  float h = sqrtf(hh);
  float u = fabsf(dd) + h;
  float gi = rsqrtf(u * u + q2);
  c = u * gi;
  float smag = apq * gi;
  s = (dd >= 0.f) ? -smag : smag;
}

// Gram partial: d += <own, partner>, n += <own, own> for 4 components.
__device__ __forceinline__ void gram4(float4 a, float& d0, float& d1,
                                      float& d2, float& d3, float& n0,
                                      float& n1, float& n2, float& n3) {
  float s0 = dpp_swap1(a.x);
  d0 += a.x * s0;
  n0 += a.x * a.x;
  float s1 = dpp_swap1(a.y);
  d1 += a.y * s1;
  n1 += a.y * a.y;
  float s2 = dpp_swap1(a.z);
  d2 += a.z * s2;
  n2 += a.z * a.z;
  float s3 = dpp_swap1(a.w);
  d3 += a.w * s3;
  n3 += a.w * a.w;
}

// Apply rotation + tournament move for 4 components. DPP reads pre-update
// partner values (result goes to a fresh value).
__device__ __forceinline__ float4 appmv4(float4 a, float c, float beta,
                                         int bpAddr) {
  float4 r;
  r.x = bperm(bpAddr, fmaf(beta, dpp_swap1(a.x), c * a.x));
  r.y = bperm(bpAddr, fmaf(beta, dpp_swap1(a.y), c * a.y));
  r.z = bperm(bpAddr, fmaf(beta, dpp_swap1(a.z), c * a.z));
  r.w = bperm(bpAddr, fmaf(beta, dpp_swap1(a.w), c * a.w));
  return r;
}

// One one-sided Jacobi round on a 20-row column held in a0..a4.
__device__ __forceinline__ void round20(float4& a0, float4& a1, float4& a2,
                                        float4& a3, float4& a4, int bpAddr,
                                        bool isP) {
  float d0 = 0.f, d1 = 0.f, d2 = 0.f, d3 = 0.f;
  float n0 = 0.f, n1 = 0.f, n2 = 0.f, n3 = 0.f;
  gram4(a0, d0, d1, d2, d3, n0, n1, n2, n3);
  gram4(a1, d0, d1, d2, d3, n0, n1, n2, n3);
  gram4(a2, d0, d1, d2, d3, n0, n1, n2, n3);
  gram4(a3, d0, d1, d2, d3, n0, n1, n2, n3);
  gram4(a4, d0, d1, d2, d3, n0, n1, n2, n3);
  float d = (d0 + d1) + (d2 + d3);
  float nOwn = (n0 + n1) + (n2 + n3);
  float nPrt = dpp_swap1(nOwn);
  float ne = isP ? nOwn : nPrt;  // canonical order: both pair lanes identical
  float no = isP ? nPrt : nOwn;
  float c, s;
  rot_cs(ne, no, d, c, s);
  float beta = isP ? -s : s;
  a0 = appmv4(a0, c, beta, bpAddr);
  a1 = appmv4(a1, c, beta, bpAddr);
  a2 = appmv4(a2, c, beta, bpAddr);
  a3 = appmv4(a3, c, beta, bpAddr);
  a4 = appmv4(a4, c, beta, bpAddr);
}

// One one-sided Jacobi round on a 16-row column held in b0..b3.
__device__ __forceinline__ void round16(float4& b0, float4& b1, float4& b2,
                                        float4& b3, int bpAddr, bool isP) {
  float d0 = 0.f, d1 = 0.f, d2 = 0.f, d3 = 0.f;
  float n0 = 0.f, n1 = 0.f, n2 = 0.f, n3 = 0.f;
  gram4(b0, d0, d1, d2, d3, n0, n1, n2, n3);
  gram4(b1, d0, d1, d2, d3, n0, n1, n2, n3);
  gram4(b2, d0, d1, d2, d3, n0, n1, n2, n3);
  gram4(b3, d0, d1, d2, d3, n0, n1, n2, n3);
  float d = (d0 + d1) + (d2 + d3);
  float nOwn = (n0 + n1) + (n2 + n3);
  float nPrt = dpp_swap1(nOwn);
  float ne = isP ? nOwn : nPrt;
  float no = isP ? nPrt : nOwn;
  float c, s;
  rot_cs(ne, no, d, c, s);
  float beta = isP ? -s : s;
  b0 = appmv4(b0, c, beta, bpAddr);
  b1 = appmv4(b1, c, beta, bpAddr);
  b2 = appmv4(b2, c, beta, bpAddr);
  b3 = appmv4(b3, c, beta, bpAddr);
}

__device__ __forceinline__ float sq4(float4 a) {
  return (a.x * a.x + a.y * a.y) + (a.z * a.z + a.w * a.w);
}

// Stage 1: X1 = w1^T X w1 (19 padded to 20), one-sided Jacobi, then
// X2 = Y^T Lamc Y with Y[j] = w2^T u_j. 3 matrices per wave (lanes 60..63
// -> shared dummy slot 6), 128-thread blocks = 6 matrices. R11 shell.
__global__ __launch_bounds__(128, 4) void spd_stage1(
    const float* __restrict__ x, const float* __restrict__ w1,
    const float* __restrict__ w2) {
  __shared__ float4 ZB[7 * 100];  // 6 real groups + 1 dummy; Z then Y rows
  __shared__ float SL[7 * 20];
  int tid = threadIdx.x;
  int wid = tid >> 6;
  int lane = tid & 63;
  int gl = lane / 20;  // 0..3 (3 = idle lanes 60..63)
  int sub = lane - gl * 20;
  bool lane_ok = (gl < 3);
  int g = lane_ok ? (wid * 3 + gl) : 6;
  int b = blockIdx.x * 6 + g;
  bool valid = lane_ok && (b < NB);
  int bm = valid ? b : 0;
  float4* ZB4 = ZB + g * 100;
  float* ZBf = (float*)ZB4;
  float* SLg = SL + g * 20;

  // ---- bilinear: Z = w1^T X (col sub), then X1 col sub = (Z w1) col ----
  const float* xb = x + bm * 361;
  float cx[19];
#pragma unroll
  for (int i = 0; i < 19; ++i) cx[i] = (sub < 19) ? xb[i * 19 + sub] : 0.f;
  float z[20];
  z[19] = 0.f;
#pragma unroll
  for (int i = 0; i < 19; ++i) {
    float acc = 0.f;
#pragma unroll
    for (int r = 0; r < 19; ++r) acc += w1[r * 19 + i] * cx[r];
    z[i] = acc;
  }
#pragma unroll
  for (int t = 0; t < 5; ++t)
    ZB4[t * 20 + sub] =
        make_float4(z[4 * t], z[4 * t + 1], z[4 * t + 2], z[4 * t + 3]);
  wsync();
  float wj[19];
#pragma unroll
  for (int r = 0; r < 19; ++r) wj[r] = (sub < 19) ? w1[r * 19 + sub] : 0.f;
  float4 a0 = make_float4(0.f, 0.f, 0.f, 0.f);
  float4 a1 = a0, a2 = a0, a3 = a0, a4 = a0;
#pragma unroll
  for (int r = 0; r < 19; ++r) {
    float wr = wj[r];
    float4 zc;
    zc = ZB4[0 * 20 + r];
    a0.x += zc.x * wr; a0.y += zc.y * wr; a0.z += zc.z * wr; a0.w += zc.w * wr;
    zc = ZB4[1 * 20 + r];
    a1.x += zc.x * wr; a1.y += zc.y * wr; a1.z += zc.z * wr; a1.w += zc.w * wr;
    zc = ZB4[2 * 20 + r];
    a2.x += zc.x * wr; a2.y += zc.y * wr; a2.z += zc.z * wr; a2.w += zc.w * wr;
    zc = ZB4[3 * 20 + r];
    a3.x += zc.x * wr; a3.y += zc.y * wr; a3.z += zc.z * wr; a3.w += zc.w * wr;
    zc = ZB4[4 * 20 + r];
    a4.x += zc.x * wr; a4.y += zc.y * wr; a4.z += zc.z * wr; a4.w += zc.w * wr;
  }
  // a0..a4 = X1 column sub; pad column 19 is exactly 0 (stays 0: d=0 => s=0).
  // Dummy lanes hold zeros: rot_cs(0,0,0) -> c=1,s=0, benign forever.

  const int bpAddr = (gl * 20 + srcslot(sub, 20)) * 4;
  const bool isP = !(sub & 1);
#pragma unroll 1
  for (int it = 0; it < 76; ++it)  // 4 sweeps (validated minimum)
    round20(a0, a1, a2, a3, a4, bpAddr, isP);

  // lambda_j = ||col||, u_j = col/||col|| (guarded for the zero pad column)
  float nOwn = ((sq4(a0) + sq4(a1)) + (sq4(a2) + sq4(a3))) + sq4(a4);
  float lamc = fmaxf(sqrtf(nOwn), EPS_REC);
  float nrm = nOwn + 1e-30f;
  float inv = rsqrtf(nrm);
  inv = inv * (1.5f - 0.5f * nrm * inv * inv);  // 1 NR step
  // Unpack to a short-lived static array for the tail (R11-proven clean).
  float cv[20];
  cv[0] = a0.x; cv[1] = a0.y; cv[2] = a0.z; cv[3] = a0.w;
  cv[4] = a1.x; cv[5] = a1.y; cv[6] = a1.z; cv[7] = a1.w;
  cv[8] = a2.x; cv[9] = a2.y; cv[10] = a2.z; cv[11] = a2.w;
  cv[12] = a3.x; cv[13] = a3.y; cv[14] = a3.z; cv[15] = a3.w;
  cv[16] = a4.x; cv[17] = a4.y; cv[18] = a4.z; cv[19] = a4.w;
  // y[k] = sum_{i<19} w2[i][k] * u_j[i]   (in-lane; w2 uniform -> scalar lds)
  float y[16];
#pragma unroll
  for (int k = 0; k < 16; ++k) y[k] = 0.f;
#pragma unroll
  for (int i = 0; i < 19; ++i) {
    float ui = cv[i];
#pragma unroll
    for (int k = 0; k < 16; ++k) y[k] += w2[i * 16 + k] * ui;
  }
#pragma unroll
  for (int k = 0; k < 16; ++k) y[k] *= inv;
  wsync();  // Z staging dead; reuse ZB for Y rows
  SLg[sub] = lamc;
#pragma unroll
  for (int t = 0; t < 4; ++t)
    ZB4[sub * 4 + t] =
        make_float4(y[4 * t], y[4 * t + 1], y[4 * t + 2], y[4 * t + 3]);
  wsync();
  // X2[i][sub] = sum_j lamc_j Y[j][i] Y[j][sub]
  if (valid && sub < 16) {
    float acc[16];
#pragma unroll
    for (int i = 0; i < 16; ++i) acc[i] = 0.f;
#pragma unroll
    for (int r = 0; r < 20; ++r) {
      float pr = SLg[r] * ZBf[r * 16 + sub];
#pragma unroll
      for (int t = 0; t < 4; ++t) {
        float4 yr = ZB4[r * 4 + t];  // Y row r, cols 4t..4t+3 (broadcast)
        acc[4 * t + 0] += pr * yr.x;
        acc[4 * t + 1] += pr * yr.y;
        acc[4 * t + 2] += pr * yr.z;
        acc[4 * t + 3] += pr * yr.w;
      }
    }
    float* outb = g_x2 + b * 256;
#pragma unroll
    for (int i = 0; i < 16; ++i) outb[i * 16 + sub] = acc[i];
  }
}

// Stage 2: one-sided Jacobi on 16x16, X3 = Y3^T Lamc Y3 with Y3[j]=w3^T u_j.
// 4 matrices per wave, 128-thread blocks = 8 matrices, all lanes active.
__global__ __launch_bounds__(128, 4) void spd_stage2(
    const float* __restrict__ w3) {
  __shared__ float4 Y3L[8 * 16];
  __shared__ float SL2[8 * 16];
  int tid = threadIdx.x;
  int wid = tid >> 6;
  int lane = tid & 63;
  int gl = lane >> 4;
  int sub = lane & 15;
  int g = wid * 4 + gl;
  int b = blockIdx.x * 8 + g;
  float* Y3f = (float*)(Y3L + g * 16);
  float* SLg = SL2 + g * 16;

  const float* xb = g_x2 + b * 256;
  float4 b0 = make_float4(xb[0 * 16 + sub], xb[1 * 16 + sub], xb[2 * 16 + sub],
                          xb[3 * 16 + sub]);
  float4 b1 = make_float4(xb[4 * 16 + sub], xb[5 * 16 + sub], xb[6 * 16 + sub],
                          xb[7 * 16 + sub]);
  float4 b2 = make_float4(xb[8 * 16 + sub], xb[9 * 16 + sub],
                          xb[10 * 16 + sub], xb[11 * 16 + sub]);
  float4 b3 = make_float4(xb[12 * 16 + sub], xb[13 * 16 + sub],
                          xb[14 * 16 + sub], xb[15 * 16 + sub]);

  const int bpAddr = (gl * 16 + srcslot(sub, 16)) * 4;
  const bool isP = !(sub & 1);
#pragma unroll 1
  for (int it = 0; it < 60; ++it)  // 4 sweeps
    round16(b0, b1, b2, b3, bpAddr, isP);

  float nOwn = (sq4(b0) + sq4(b1)) + (sq4(b2) + sq4(b3));
  float lamc = fmaxf(sqrtf(nOwn), EPS_REC);
  float nrm = nOwn + 1e-30f;
  float inv = rsqrtf(nrm);
  inv = inv * (1.5f - 0.5f * nrm * inv * inv);
  float cv[16];
  cv[0] = b0.x; cv[1] = b0.y; cv[2] = b0.z; cv[3] = b0.w;
  cv[4] = b1.x; cv[5] = b1.y; cv[6] = b1.z; cv[7] = b1.w;
  cv[8] = b2.x; cv[9] = b2.y; cv[10] = b2.z; cv[11] = b2.w;
  cv[12] = b3.x; cv[13] = b3.y; cv[14] = b3.z; cv[15] = b3.w;
  float y3[4] = {0.f, 0.f, 0.f, 0.f};
#pragma unroll
  for (int i = 0; i < 16; ++i) {
    float ui = cv[i];
#pragma unroll
    for (int j = 0; j < 4; ++j) y3[j] += w3[i * 4 + j] * ui;
  }
#pragma unroll
  for (int j = 0; j < 4; ++j) y3[j] *= inv;
  SLg[sub] = lamc;
  ((float4*)Y3f)[sub] = make_float4(y3[0], y3[1], y3[2], y3[3]);
  wsync();
  int ii = sub >> 2, jj = sub & 3;
  float acc = 0.f;
#pragma unroll
  for (int r = 0; r < 16; ++r)
    acc += SLg[r] * Y3f[r * 4 + ii] * Y3f[r * 4 + jj];
  g_x3[b * 16 + sub] = acc;
}

// Stage 3: per-thread 4x4 LogEig in registers, FC(16->2), log_softmax.
__global__ __launch_bounds__(256) void spd_stage3(const float* __restrict__ fcw,
                                                  float* __restrict__ out) {
  int b = blockIdx.x * 256 + threadIdx.x;
  const float* xb = g_x3 + b * 16;
  float a[4][4];
#pragma unroll
  for (int i = 0; i < 4; ++i)
#pragma unroll
    for (int j = 0; j < 4; ++j) a[i][j] = xb[i * 4 + j];
  float vv[4][4];
#pragma unroll
  for (int i = 0; i < 4; ++i)
#pragma unroll
    for (int j = 0; j < 4; ++j) vv[i][j] = (i == j) ? 1.f : 0.f;

  constexpr int P4[6] = {0, 0, 0, 1, 1, 2};
  constexpr int Q4[6] = {1, 2, 3, 2, 3, 3};
  for (int sw = 0; sw < 6; ++sw) {
#pragma unroll
    for (int e = 0; e < 6; ++e) {
      const int p = P4[e], q = Q4[e];
      float c, s;
      rot_cs(a[p][p], a[q][q], a[p][q], c, s);
#pragma unroll
      for (int j = 0; j < 4; ++j) {
        float xx = a[p][j], yy = a[q][j];
        a[p][j] = c * xx - s * yy;
        a[q][j] = s * xx + c * yy;
      }
#pragma unroll
      for (int i = 0; i < 4; ++i) {
        float xx = a[i][p], yy = a[i][q];
        a[i][p] = c * xx - s * yy;
        a[i][q] = s * xx + c * yy;
      }
#pragma unroll
      for (int i = 0; i < 4; ++i) {
        float xx = vv[i][p], yy = vv[i][q];
        vv[i][p] = c * xx - s * yy;
        vv[i][q] = s * xx + c * yy;
      }
    }
  }
  float ll[4];
#pragma unroll
  for (int r = 0; r < 4; ++r) ll[r] = logf(fmaxf(a[r][r], 1e-12f));
  float feat[16];
#pragma unroll
  for (int i = 0; i < 4; ++i)
#pragma unroll
    for (int j = 0; j < 4; ++j) {
      float acc = 0.f;
#pragma unroll
      for (int r = 0; r < 4; ++r) acc += ll[r] * vv[i][r] * vv[j][r];
      feat[i * 4 + j] = acc;
    }
  float z0 = 0.f, z1 = 0.f;
#pragma unroll
  for (int k = 0; k < 16; ++k) {
    z0 += feat[k] * fcw[2 * k + 0];
    z1 += feat[k] * fcw[2 * k + 1];
  }
  float m = fmaxf(z0, z1);
  float lse = logf(expf(z0 - m) + expf(z1 - m));
  out[b * 2 + 0] = z0 - m - lse;
  out[b * 2 + 1] = z1 - m - lse;
#pragma unroll
  for (int k = 0; k < 16; ++k) out[2 * NB + b * 16 + k] = feat[k];
}

extern "C" void kernel_launch(void* const* d_in, const int* in_sizes, int n_in,
                              void* d_out, int out_size, void* d_ws,
                              size_t ws_size, hipStream_t stream) {
  (void)in_sizes;
  (void)n_in;
  (void)out_size;
  (void)d_ws;
  (void)ws_size;
  const float* x = (const float*)d_in[0];
  const float* w1 = (const float*)d_in[1];
  const float* w2 = (const float*)d_in[2];
  const float* w3 = (const float*)d_in[3];
  const float* fcw = (const float*)d_in[4];
  float* out = (float*)d_out;

  spd_stage1<<<(NB + 5) / 6, 128, 0, stream>>>(x, w1, w2);
  spd_stage2<<<NB / 8, 128, 0, stream>>>(w3);
  spd_stage3<<<NB / 256, 256, 0, stream>>>(fcw, out);
}

// Round 8
// 633.878 us; speedup vs baseline: 1.0388x; 1.0204x over previous
//
#include <hip/hip_runtime.h>
#include <math.h>

#define NB 32768
#define EPS_REC 1e-4f

// Inter-stage staging (static device globals: graph-capture safe).
__device__ float g_x2[NB * 256];  // stage-1 output: B x 16 x 16
__device__ float g_x3[NB * 16];   // stage-2 output: B x 4 x 4

// HISTORY (do not regress):
//  R5: dual-chain ILP -> occupancy halved, +22% time.
//  R6: __launch_bounds__(128,6) -> 85-reg cap -> spills (FETCH 407MB), +60%.
//  R8: 3 sweeps -> absmax 1.375 FAIL. 4 sweeps minimum (plateau 0.25).
//  R9/R10: two-sided, U in regs, 128-thr blocks: 641us, FETCH 23MB -- the
//       register-overflow path was AGPR shuttle (v_accvgpr), NOT scratch.
//  R11: U in LDS: +10%. Shell (128-thr, valid-mask, (128,4)): ZERO scratch.
//  R12: ONE-SIDED Jacobi (named-reg col, DPP partner, bperm tournament):
//       PASSED (absmax 0.5) but FETCH 492/WRITE 961MB scratch.
//  R13-R16: swp[] removal / float4-SSA / waves_per_eu(4,4) / LDS-pad: ALL
//       inert on scratch+VGPR(=64).
//  R17: R11 shell transplant: STILL 439/857MB. Scratch is invariant to
//       shell, form, and budget knobs => the trigger is the round body.
//       WRITE/threads = ~16B/round = ONE float4 spilled per round: marginal
//       pressure overflow from pre-RA scheduler batching 20 DPP / 20 bperm
//       temps into one giant scheduling region (R9's LDS ops naturally
//       chunked the region; the pure-register round gives one big region).
//  R18 (this): cap scheduling regions: sched_barrier(0) after EVERY float4
//       chunk in gram+apply; gram accumulators 8 -> 4. Peak pressure ~34.
//       Shell and everything else identical to R17.
__device__ __forceinline__ void wsync() {
  asm volatile("" ::: "memory");
  __builtin_amdgcn_wave_barrier();
  asm volatile("" ::: "memory");
}

__device__ __forceinline__ void sbar() { __builtin_amdgcn_sched_barrier(0); }

// Swap values between adjacent lanes (lane ^ 1) via DPP quad_perm [1,0,3,2].
// Pairs (2k,2k+1) are even-aligned so they never cross a quad. VALU-pipe op.
__device__ __forceinline__ float dpp_swap1(float x) {
  int xi = __builtin_bit_cast(int, x);
  int yi = __builtin_amdgcn_update_dpp(xi, xi, 0xB1, 0xF, 0xF, true);
  return __builtin_bit_cast(float, yi);
}

// Lane-pull via LDS crossbar (conflict-free permutation). addr = 4*srcLane
// (wave-relative lane index).
__device__ __forceinline__ float bperm(int addr, float v) {
  int r = __builtin_amdgcn_ds_bpermute(addr, __builtin_bit_cast(int, v));
  return __builtin_bit_cast(float, r);
}

// Tournament (circle-method): content of slot s moves to permf(s); with fixed
// pairing (2k,2k+1), every pair meets exactly once per N-1 rounds.
// srcslot = permf^{-1}: the slot whose content lands in slot `sub`.
__device__ __forceinline__ int srcslot(int sub, int n) {
  return sub == 0 ? 0
       : sub == 1 ? 2
       : sub == n - 2 ? n - 1
       : (sub & 1) ? sub - 2 : sub + 2;
}

// Jacobi rotation (c,s) zeroing the (p,q) off-diagonal of the 2x2 Gram
// [[app,apq],[apq,aqq]]; G = [[c,s],[-s,c]].
__device__ __forceinline__ void rot_cs(float app, float aqq, float apq,
                                       float& c, float& s) {
  float dd = 0.5f * (app - aqq);
  float q2 = apq * apq;
  float hh = dd * dd + q2 + 1e-30f;
  float h = sqrtf(hh);
  float u = fabsf(dd) + h;
  float gi = rsqrtf(u * u + q2);
  c = u * gi;
  float smag = apq * gi;
  s = (dd >= 0.f) ? -smag : smag;
}

// Gram partial over one float4: d/n split into 2 accumulators each.
__device__ __forceinline__ void gram4(float4 a, float& d0, float& d1,
                                      float& n0, float& n1) {
  float s0 = dpp_swap1(a.x);
  d0 += a.x * s0;
  n0 += a.x * a.x;
  float s1 = dpp_swap1(a.y);
  d1 += a.y * s1;
  n1 += a.y * a.y;
  float s2 = dpp_swap1(a.z);
  d0 += a.z * s2;
  n0 += a.z * a.z;
  float s3 = dpp_swap1(a.w);
  d1 += a.w * s3;
  n1 += a.w * a.w;
}

// Apply rotation + tournament move for 4 components. DPP reads pre-update
// partner values (result goes to a fresh value).
__device__ __forceinline__ float4 appmv4(float4 a, float c, float beta,
                                         int bpAddr) {
  float4 r;
  r.x = bperm(bpAddr, fmaf(beta, dpp_swap1(a.x), c * a.x));
  r.y = bperm(bpAddr, fmaf(beta, dpp_swap1(a.y), c * a.y));
  r.z = bperm(bpAddr, fmaf(beta, dpp_swap1(a.z), c * a.z));
  r.w = bperm(bpAddr, fmaf(beta, dpp_swap1(a.w), c * a.w));
  return r;
}

// One one-sided Jacobi round on a 20-row column held in a0..a4.
// sched_barrier(0) after every chunk caps the pre-RA scheduling region so
// at most 4 DPP/bperm temps are in flight -> no pressure overflow (R18).
__device__ __forceinline__ void round20(float4& a0, float4& a1, float4& a2,
                                        float4& a3, float4& a4, int bpAddr,
                                        bool isP) {
  float d0 = 0.f, d1 = 0.f, n0 = 0.f, n1 = 0.f;
  gram4(a0, d0, d1, n0, n1);
  sbar();
  gram4(a1, d0, d1, n0, n1);
  sbar();
  gram4(a2, d0, d1, n0, n1);
  sbar();
  gram4(a3, d0, d1, n0, n1);
  sbar();
  gram4(a4, d0, d1, n0, n1);
  sbar();
  float d = d0 + d1;
  float nOwn = n0 + n1;
  float nPrt = dpp_swap1(nOwn);
  float ne = isP ? nOwn : nPrt;  // canonical order: both pair lanes identical
  float no = isP ? nPrt : nOwn;
  float c, s;
  rot_cs(ne, no, d, c, s);
  float beta = isP ? -s : s;
  sbar();
  a0 = appmv4(a0, c, beta, bpAddr);
  sbar();
  a1 = appmv4(a1, c, beta, bpAddr);
  sbar();
  a2 = appmv4(a2, c, beta, bpAddr);
  sbar();
  a3 = appmv4(a3, c, beta, bpAddr);
  sbar();
  a4 = appmv4(a4, c, beta, bpAddr);
  sbar();
}

// One one-sided Jacobi round on a 16-row column held in b0..b3.
__device__ __forceinline__ void round16(float4& b0, float4& b1, float4& b2,
                                        float4& b3, int bpAddr, bool isP) {
  float d0 = 0.f, d1 = 0.f, n0 = 0.f, n1 = 0.f;
  gram4(b0, d0, d1, n0, n1);
  sbar();
  gram4(b1, d0, d1, n0, n1);
  sbar();
  gram4(b2, d0, d1, n0, n1);
  sbar();
  gram4(b3, d0, d1, n0, n1);
  sbar();
  float d = d0 + d1;
  float nOwn = n0 + n1;
  float nPrt = dpp_swap1(nOwn);
  float ne = isP ? nOwn : nPrt;
  float no = isP ? nPrt : nOwn;
  float c, s;
  rot_cs(ne, no, d, c, s);
  float beta = isP ? -s : s;
  sbar();
  b0 = appmv4(b0, c, beta, bpAddr);
  sbar();
  b1 = appmv4(b1, c, beta, bpAddr);
  sbar();
  b2 = appmv4(b2, c, beta, bpAddr);
  sbar();
  b3 = appmv4(b3, c, beta, bpAddr);
  sbar();
}

__device__ __forceinline__ float sq4(float4 a) {
  return (a.x * a.x + a.y * a.y) + (a.z * a.z + a.w * a.w);
}

// Stage 1: X1 = w1^T X w1 (19 padded to 20), one-sided Jacobi, then
// X2 = Y^T Lamc Y with Y[j] = w2^T u_j. 3 matrices per wave (lanes 60..63
// -> shared dummy slot 6), 128-thread blocks = 6 matrices. R11 shell.
__global__ __launch_bounds__(128, 4) void spd_stage1(
    const float* __restrict__ x, const float* __restrict__ w1,
    const float* __restrict__ w2) {
  __shared__ float4 ZB[7 * 100];  // 6 real groups + 1 dummy; Z then Y rows
  __shared__ float SL[7 * 20];
  int tid = threadIdx.x;
  int wid = tid >> 6;
  int lane = tid & 63;
  int gl = lane / 20;  // 0..3 (3 = idle lanes 60..63)
  int sub = lane - gl * 20;
  bool lane_ok = (gl < 3);
  int g = lane_ok ? (wid * 3 + gl) : 6;
  int b = blockIdx.x * 6 + g;
  bool valid = lane_ok && (b < NB);
  int bm = valid ? b : 0;
  float4* ZB4 = ZB + g * 100;
  float* ZBf = (float*)ZB4;
  float* SLg = SL + g * 20;

  // ---- bilinear: Z = w1^T X (col sub), then X1 col sub = (Z w1) col ----
  const float* xb = x + bm * 361;
  float cx[19];
#pragma unroll
  for (int i = 0; i < 19; ++i) cx[i] = (sub < 19) ? xb[i * 19 + sub] : 0.f;
  float z[20];
  z[19] = 0.f;
#pragma unroll
  for (int i = 0; i < 19; ++i) {
    float acc = 0.f;
#pragma unroll
    for (int r = 0; r < 19; ++r) acc += w1[r * 19 + i] * cx[r];
    z[i] = acc;
  }
#pragma unroll
  for (int t = 0; t < 5; ++t)
    ZB4[t * 20 + sub] =
        make_float4(z[4 * t], z[4 * t + 1], z[4 * t + 2], z[4 * t + 3]);
  wsync();
  float wj[19];
#pragma unroll
  for (int r = 0; r < 19; ++r) wj[r] = (sub < 19) ? w1[r * 19 + sub] : 0.f;
  float4 a0 = make_float4(0.f, 0.f, 0.f, 0.f);
  float4 a1 = a0, a2 = a0, a3 = a0, a4 = a0;
#pragma unroll
  for (int r = 0; r < 19; ++r) {
    float wr = wj[r];
    float4 zc;
    zc = ZB4[0 * 20 + r];
    a0.x += zc.x * wr; a0.y += zc.y * wr; a0.z += zc.z * wr; a0.w += zc.w * wr;
    zc = ZB4[1 * 20 + r];
    a1.x += zc.x * wr; a1.y += zc.y * wr; a1.z += zc.z * wr; a1.w += zc.w * wr;
    zc = ZB4[2 * 20 + r];
    a2.x += zc.x * wr; a2.y += zc.y * wr; a2.z += zc.z * wr; a2.w += zc.w * wr;
    zc = ZB4[3 * 20 + r];
    a3.x += zc.x * wr; a3.y += zc.y * wr; a3.z += zc.z * wr; a3.w += zc.w * wr;
    zc = ZB4[4 * 20 + r];
    a4.x += zc.x * wr; a4.y += zc.y * wr; a4.z += zc.z * wr; a4.w += zc.w * wr;
  }
  // a0..a4 = X1 column sub; pad column 19 is exactly 0 (stays 0: d=0 => s=0).
  // Dummy lanes hold zeros: rot_cs(0,0,0) -> c=1,s=0, benign forever.

  const int bpAddr = (gl * 20 + srcslot(sub, 20)) * 4;
  const bool isP = !(sub & 1);
#pragma unroll 1
  for (int it = 0; it < 76; ++it)  // 4 sweeps (validated minimum)
    round20(a0, a1, a2, a3, a4, bpAddr, isP);

  // lambda_j = ||col||, u_j = col/||col|| (guarded for the zero pad column)
  float nOwn = ((sq4(a0) + sq4(a1)) + (sq4(a2) + sq4(a3))) + sq4(a4);
  float lamc = fmaxf(sqrtf(nOwn), EPS_REC);
  float nrm = nOwn + 1e-30f;
  float inv = rsqrtf(nrm);
  inv = inv * (1.5f - 0.5f * nrm * inv * inv);  // 1 NR step
  // Unpack to a short-lived static array for the tail (R11-proven clean).
  float cv[20];
  cv[0] = a0.x; cv[1] = a0.y; cv[2] = a0.z; cv[3] = a0.w;
  cv[4] = a1.x; cv[5] = a1.y; cv[6] = a1.z; cv[7] = a1.w;
  cv[8] = a2.x; cv[9] = a2.y; cv[10] = a2.z; cv[11] = a2.w;
  cv[12] = a3.x; cv[13] = a3.y; cv[14] = a3.z; cv[15] = a3.w;
  cv[16] = a4.x; cv[17] = a4.y; cv[18] = a4.z; cv[19] = a4.w;
  // y[k] = sum_{i<19} w2[i][k] * u_j[i]   (in-lane; w2 uniform -> scalar lds)
  float y[16];
#pragma unroll
  for (int k = 0; k < 16; ++k) y[k] = 0.f;
#pragma unroll
  for (int i = 0; i < 19; ++i) {
    float ui = cv[i];
#pragma unroll
    for (int k = 0; k < 16; ++k) y[k] += w2[i * 16 + k] * ui;
  }
#pragma unroll
  for (int k = 0; k < 16; ++k) y[k] *= inv;
  wsync();  // Z staging dead; reuse ZB for Y rows
  SLg[sub] = lamc;
#pragma unroll
  for (int t = 0; t < 4; ++t)
    ZB4[sub * 4 + t] =
        make_float4(y[4 * t], y[4 * t + 1], y[4 * t + 2], y[4 * t + 3]);
  wsync();
  // X2[i][sub] = sum_j lamc_j Y[j][i] Y[j][sub]
  if (valid && sub < 16) {
    float acc[16];
#pragma unroll
    for (int i = 0; i < 16; ++i) acc[i] = 0.f;
#pragma unroll
    for (int r = 0; r < 20; ++r) {
      float pr = SLg[r] * ZBf[r * 16 + sub];
#pragma unroll
      for (int t = 0; t < 4; ++t) {
        float4 yr = ZB4[r * 4 + t];  // Y row r, cols 4t..4t+3 (broadcast)
        acc[4 * t + 0] += pr * yr.x;
        acc[4 * t + 1] += pr * yr.y;
        acc[4 * t + 2] += pr * yr.z;
        acc[4 * t + 3] += pr * yr.w;
      }
    }
    float* outb = g_x2 + b * 256;
#pragma unroll
    for (int i = 0; i < 16; ++i) outb[i * 16 + sub] = acc[i];
  }
}

// Stage 2: one-sided Jacobi on 16x16, X3 = Y3^T Lamc Y3 with Y3[j]=w3^T u_j.
// 4 matrices per wave, 128-thread blocks = 8 matrices, all lanes active.
__global__ __launch_bounds__(128, 4) void spd_stage2(
    const float* __restrict__ w3) {
  __shared__ float4 Y3L[8 * 16];
  __shared__ float SL2[8 * 16];
  int tid = threadIdx.x;
  int wid = tid >> 6;
  int lane = tid & 63;
  int gl = lane >> 4;
  int sub = lane & 15;
  int g = wid * 4 + gl;
  int b = blockIdx.x * 8 + g;
  float* Y3f = (float*)(Y3L + g * 16);
  float* SLg = SL2 + g * 16;

  const float* xb = g_x2 + b * 256;
  float4 b0 = make_float4(xb[0 * 16 + sub], xb[1 * 16 + sub], xb[2 * 16 + sub],
                          xb[3 * 16 + sub]);
  float4 b1 = make_float4(xb[4 * 16 + sub], xb[5 * 16 + sub], xb[6 * 16 + sub],
                          xb[7 * 16 + sub]);
  float4 b2 = make_float4(xb[8 * 16 + sub], xb[9 * 16 + sub],
                          xb[10 * 16 + sub], xb[11 * 16 + sub]);
  float4 b3 = make_float4(xb[12 * 16 + sub], xb[13 * 16 + sub],
                          xb[14 * 16 + sub], xb[15 * 16 + sub]);

  const int bpAddr = (gl * 16 + srcslot(sub, 16)) * 4;
  const bool isP = !(sub & 1);
#pragma unroll 1
  for (int it = 0; it < 60; ++it)  // 4 sweeps
    round16(b0, b1, b2, b3, bpAddr, isP);

  float nOwn = (sq4(b0) + sq4(b1)) + (sq4(b2) + sq4(b3));
  float lamc = fmaxf(sqrtf(nOwn), EPS_REC);
  float nrm = nOwn + 1e-30f;
  float inv = rsqrtf(nrm);
  inv = inv * (1.5f - 0.5f * nrm * inv * inv);
  float cv[16];
  cv[0] = b0.x; cv[1] = b0.y; cv[2] = b0.z; cv[3] = b0.w;
  cv[4] = b1.x; cv[5] = b1.y; cv[6] = b1.z; cv[7] = b1.w;
  cv[8] = b2.x; cv[9] = b2.y; cv[10] = b2.z; cv[11] = b2.w;
  cv[12] = b3.x; cv[13] = b3.y; cv[14] = b3.z; cv[15] = b3.w;
  float y3[4] = {0.f, 0.f, 0.f, 0.f};
#pragma unroll
  for (int i = 0; i < 16; ++i) {
    float ui = cv[i];
#pragma unroll
    for (int j = 0; j < 4; ++j) y3[j] += w3[i * 4 + j] * ui;
  }
#pragma unroll
  for (int j = 0; j < 4; ++j) y3[j] *= inv;
  SLg[sub] = lamc;
  ((float4*)Y3f)[sub] = make_float4(y3[0], y3[1], y3[2], y3[3]);
  wsync();
  int ii = sub >> 2, jj = sub & 3;
  float acc = 0.f;
#pragma unroll
  for (int r = 0; r < 16; ++r)
    acc += SLg[r] * Y3f[r * 4 + ii] * Y3f[r * 4 + jj];
  g_x3[b * 16 + sub] = acc;
}

// Stage 3: per-thread 4x4 LogEig in registers, FC(16->2), log_softmax.
__global__ __launch_bounds__(256) void spd_stage3(const float* __restrict__ fcw,
                                                  float* __restrict__ out) {
  int b = blockIdx.x * 256 + threadIdx.x;
  const float* xb = g_x3 + b * 16;
  float a[4][4];
#pragma unroll
  for (int i = 0; i < 4; ++i)
#pragma unroll
    for (int j = 0; j < 4; ++j) a[i][j] = xb[i * 4 + j];
  float vv[4][4];
#pragma unroll
  for (int i = 0; i < 4; ++i)
#pragma unroll
    for (int j = 0; j < 4; ++j) vv[i][j] = (i == j) ? 1.f : 0.f;

  constexpr int P4[6] = {0, 0, 0, 1, 1, 2};
  constexpr int Q4[6] = {1, 2, 3, 2, 3, 3};
  for (int sw = 0; sw < 6; ++sw) {
#pragma unroll
    for (int e = 0; e < 6; ++e) {
      const int p = P4[e], q = Q4[e];
      float c, s;
      rot_cs(a[p][p], a[q][q], a[p][q], c, s);
#pragma unroll
      for (int j = 0; j < 4; ++j) {
        float xx = a[p][j], yy = a[q][j];
        a[p][j] = c * xx - s * yy;
        a[q][j] = s * xx + c * yy;
      }
#pragma unroll
      for (int i = 0; i < 4; ++i) {
        float xx = a[i][p], yy = a[i][q];
        a[i][p] = c * xx - s * yy;
        a[i][q] = s * xx + c * yy;
      }
#pragma unroll
      for (int i = 0; i < 4; ++i) {
        float xx = vv[i][p], yy = vv[i][q];
        vv[i][p] = c * xx - s * yy;
        vv[i][q] = s * xx + c * yy;
      }
    }
  }
  float ll[4];
#pragma unroll
  for (int r = 0; r < 4; ++r) ll[r] = logf(fmaxf(a[r][r], 1e-12f));
  float feat[16];
#pragma unroll
  for (int i = 0; i < 4; ++i)
#pragma unroll
    for (int j = 0; j < 4; ++j) {
      float acc = 0.f;
#pragma unroll
      for (int r = 0; r < 4; ++r) acc += ll[r] * vv[i][r] * vv[j][r];
      feat[i * 4 + j] = acc;
    }
  float z0 = 0.f, z1 = 0.f;
#pragma unroll
  for (int k = 0; k < 16; ++k) {
    z0 += feat[k] * fcw[2 * k + 0];
    z1 += feat[k] * fcw[2 * k + 1];
  }
  float m = fmaxf(z0, z1);
  float lse = logf(expf(z0 - m) + expf(z1 - m));
  out[b * 2 + 0] = z0 - m - lse;
  out[b * 2 + 1] = z1 - m - lse;
#pragma unroll
  for (int k = 0; k < 16; ++k) out[2 * NB + b * 16 + k] = feat[k];
}

extern "C" void kernel_launch(void* const* d_in, const int* in_sizes, int n_in,
                              void* d_out, int out_size, void* d_ws,
                              size_t ws_size, hipStream_t stream) {
  (void)in_sizes;
  (void)n_in;
  (void)out_size;
  (void)d_ws;
  (void)ws_size;
  const float* x = (const float*)d_in[0];
  const float* w1 = (const float*)d_in[1];
  const float* w2 = (const float*)d_in[2];
  const float* w3 = (const float*)d_in[3];
  const float* fcw = (const float*)d_in[4];
  float* out = (float*)d_out;

  spd_stage1<<<(NB + 5) / 6, 128, 0, stream>>>(x, w1, w2);
  spd_stage2<<<NB / 8, 128, 0, stream>>>(w3);
  spd_stage3<<<NB / 256, 256, 0, stream>>>(fcw, out);
}